// Round 4
// baseline (85.093 us; speedup 1.0000x reference)
//
#include <hip/hip_runtime.h>
#include <hip/hip_fp16.h>
#include <math.h>

#define NROWS 50000
#define D 128
#define KNB 16

typedef _Float16 f16;
typedef _Float16 f16x8 __attribute__((ext_vector_type(8)));
typedef _Float16 f16x2 __attribute__((ext_vector_type(2)));
typedef float f32x4 __attribute__((ext_vector_type(4)));

// ---- fused kernel: W->LDS(f16,swizzled); per wave (16 rows): fphn(normalized), [Yh|base] ----
// 512 threads = 8 waves = 128 rows per block. LDS 64KB -> 391 blocks all co-resident (2/CU cap).
__global__ __launch_bounds__(512) void gemm_kernel(const float* __restrict__ fp,
                                                   const float* __restrict__ W,
                                                   const float* __restrict__ b,
                                                   f16* __restrict__ fphn,
                                                   f16* __restrict__ Yh,
                                                   float* __restrict__ base) {
    __shared__ f16 wlds[256 * 128];  // Wcat[col][k], chunk-swizzled: chunk ^= (col&15)
    int tid = threadIdx.x;

    // stage W (128x256 f32) -> LDS as f16 concat layout, coalesced 32B reads per thread
    #pragma unroll
    for (int it = 0; it < 8; ++it) {
        int g = tid + it * 512;          // 8-float group, 4096 total
        int i = g * 8;                   // flat index into W
        int c_w = i >> 8;                // W row (0..127)
        int kk = i & 255;                // W col (0..255)
        int destrow = (kk < 128) ? c_w : c_w + 128;
        int k = kk & 127;
        int chunk = (k >> 3) ^ (destrow & 15);
        f32x4 v0 = *(const f32x4*)(W + i);
        f32x4 v1 = *(const f32x4*)(W + i + 4);
        f16x8 h;
        #pragma unroll
        for (int e = 0; e < 4; ++e) { h[e] = (f16)v0[e]; h[4 + e] = (f16)v1[e]; }
        *(f16x8*)(wlds + destrow * 128 + chunk * 8) = h;
    }
    __syncthreads();

    int wid = tid >> 6, lane = tid & 63;
    int row0 = blockIdx.x * 128 + wid * 16;
    if (row0 >= NROWS) return;           // no barriers after this point
    int r = lane & 15, kg = lane >> 4;

    // load row slices f32, compute sum-of-squares, then emit A-frags + normalized fphn
    const float* src = fp + (size_t)(row0 + r) * D + kg * 8;
    f32x4 v[8];
    float ssq = 0.f;
    #pragma unroll
    for (int kc = 0; kc < 4; ++kc) {
        v[2 * kc]     = *(const f32x4*)(src + kc * 32);
        v[2 * kc + 1] = *(const f32x4*)(src + kc * 32 + 4);
        #pragma unroll
        for (int e = 0; e < 4; ++e) {
            ssq = fmaf(v[2 * kc][e], v[2 * kc][e], ssq);
            ssq = fmaf(v[2 * kc + 1][e], v[2 * kc + 1][e], ssq);
        }
    }
    ssq += __shfl_xor(ssq, 16, 64);
    ssq += __shfl_xor(ssq, 32, 64);      // all lanes: full row ssq
    float rn = rsqrtf(ssq);

    f16x8 a[4];
    #pragma unroll
    for (int kc = 0; kc < 4; ++kc) {
        f16x8 h, hn;
        #pragma unroll
        for (int e = 0; e < 4; ++e) {
            float x0 = v[2 * kc][e], x1 = v[2 * kc + 1][e];
            h[e] = (f16)x0;                h[4 + e] = (f16)x1;
            hn[e] = (f16)(x0 * rn);        hn[4 + e] = (f16)(x1 * rn);
        }
        a[kc] = h;
        *(f16x8*)(fphn + (size_t)(row0 + r) * D + kc * 32 + kg * 8) = hn;
    }

    #pragma unroll 4
    for (int ct = 0; ct < 16; ++ct) {
        int col = ct * 16 + r;
        f32x4 acc = {0.f, 0.f, 0.f, 0.f};
        #pragma unroll
        for (int kc = 0; kc < 4; ++kc) {
            int sc = (kc * 4 + kg) ^ r;  // swizzled chunk (matches staging XOR)
            f16x8 bf = *(const f16x8*)(wlds + col * 128 + sc * 8);
            acc = __builtin_amdgcn_mfma_f32_16x16x32_f16(a[kc], bf, acc, 0, 0, 0);
        }
        // C/D: col = lane&15 -> output channel; rows = row0 + kg*4 + i
        if (col < 128) {
            #pragma unroll
            for (int i = 0; i < 4; ++i)
                Yh[(size_t)(row0 + kg * 4 + i) * D + col] = (f16)acc[i];
        } else {
            float bias = b[col - 128];
            #pragma unroll
            for (int i = 0; i < 4; ++i)
                base[(size_t)(row0 + kg * 4 + i) * D + (col - 128)] = acc[i] + bias;
        }
    }
}

// ---- main: TWO n per wave; all 32 Y-gathers + both cosine operand sets in flight ----
__global__ __launch_bounds__(256) void main_kernel(const f16* __restrict__ fphn,
                                                   const int* __restrict__ idx,
                                                   const f16* __restrict__ Yh,
                                                   float* __restrict__ out) {
    int wid = threadIdx.x >> 6, lane = threadIdx.x & 63;
    int g = blockIdx.x * 4 + wid;
    int n0 = g * 2, n1 = n0 + 1;
    int s = lane & 3, k = lane >> 2;

    int j0 = idx[n0 * KNB + k];
    int j1 = idx[n1 * KNB + k];

    // issue the full gather set up front (memory-level parallelism)
    f16x2 yv0[16], yv1[16];
    #pragma unroll
    for (int kk = 0; kk < KNB; ++kk) {
        int jk = __shfl(j0, kk * 4, 64);
        yv0[kk] = *(const f16x2*)(Yh + (size_t)jk * D + lane * 2);
    }
    #pragma unroll
    for (int kk = 0; kk < KNB; ++kk) {
        int jk = __shfl(j1, kk * 4, 64);
        yv1[kk] = *(const f16x2*)(Yh + (size_t)jk * D + lane * 2);
    }
    float2 bv0 = *(const float2*)(out + (size_t)n0 * D + lane * 2);
    float2 bv1 = *(const float2*)(out + (size_t)n1 * D + lane * 2);

    // cosine dots on pre-normalized rows: w = dot directly
    const f16x8* aj0 = (const f16x8*)(fphn + (size_t)j0 * D + s * 32);
    const f16x8* an0 = (const f16x8*)(fphn + (size_t)n0 * D + s * 32);
    const f16x8* aj1 = (const f16x8*)(fphn + (size_t)j1 * D + s * 32);
    const f16x8* an1 = (const f16x8*)(fphn + (size_t)n1 * D + s * 32);
    float p0 = 0.f, p1 = 0.f;
    #pragma unroll
    for (int q = 0; q < 4; ++q) {
        f16x8 x0 = aj0[q], y0 = an0[q], x1 = aj1[q], y1 = an1[q];
        #pragma unroll
        for (int e = 0; e < 8; ++e) {
            p0 += (float)x0[e] * (float)y0[e];
            p1 += (float)x1[e] * (float)y1[e];
        }
    }
    p0 += __shfl_xor(p0, 1, 64);
    p0 += __shfl_xor(p0, 2, 64);
    p1 += __shfl_xor(p1, 1, 64);
    p1 += __shfl_xor(p1, 2, 64);

    // combine: lane owns cols 2*lane, 2*lane+1
    float a00 = -INFINITY, a01 = -INFINITY, a10 = -INFINITY, a11 = -INFINITY;
    #pragma unroll
    for (int kk = 0; kk < KNB; ++kk) {
        float w0 = __shfl(p0, kk * 4, 64);
        float w1 = __shfl(p1, kk * 4, 64);
        a00 = fmaxf(a00, ((float)yv0[kk].x + bv0.x) * w0);
        a01 = fmaxf(a01, ((float)yv0[kk].y + bv0.y) * w0);
        a10 = fmaxf(a10, ((float)yv1[kk].x + bv1.x) * w1);
        a11 = fmaxf(a11, ((float)yv1[kk].y + bv1.y) * w1);
    }
    *(float2*)(out + (size_t)n0 * D + lane * 2) = make_float2(a00, a01);
    *(float2*)(out + (size_t)n1 * D + lane * 2) = make_float2(a10, a11);
}

extern "C" void kernel_launch(void* const* d_in, const int* in_sizes, int n_in,
                              void* d_out, int out_size, void* d_ws, size_t ws_size,
                              hipStream_t stream) {
    const float* fp  = (const float*)d_in[0];   // (N,128) f32
    const int*   idx = (const int*)d_in[1];     // (N,16) int32
    const float* W   = (const float*)d_in[2];   // (128,256) f32
    const float* b   = (const float*)d_in[3];   // (128,) f32
    float* out = (float*)d_out;                 // (N,128) f32; holds base between kernels

    char* ws = (char*)d_ws;
    f16* fphn = (f16*)ws;                                  // 12.8 MB (pre-normalized rows)
    f16* Yh   = (f16*)(ws + (size_t)NROWS * D * 2);        // 12.8 MB

    gemm_kernel<<<(NROWS + 127) / 128, 512, 0, stream>>>(fp, W, b, fphn, Yh, out);
    main_kernel<<<(NROWS / 2 + 3) / 4, 256, 0, stream>>>(fphn, idx, Yh, out);
}

// Round 5
// 65.989 us; speedup vs baseline: 1.2895x; 1.2895x over previous
//
#include <hip/hip_runtime.h>
#include <hip/hip_fp16.h>
#include <math.h>

#define NROWS 50000
#define D 128
#define KNB 16

typedef _Float16 f16;
typedef _Float16 f16x8 __attribute__((ext_vector_type(8)));
typedef _Float16 f16x2 __attribute__((ext_vector_type(2)));
typedef float f32x4 __attribute__((ext_vector_type(4)));
typedef float f32x2 __attribute__((ext_vector_type(2)));
typedef unsigned int u32;

// ---- fused kernel: W->LDS(f16,swizzled); per wave (16 rows): fp8-normalized row, [Yh|base] ----
// 512 threads = 8 waves = 128 rows per block. LDS 64KB.
__global__ __launch_bounds__(512) void gemm_kernel(const float* __restrict__ fp,
                                                   const float* __restrict__ W,
                                                   const float* __restrict__ b,
                                                   unsigned char* __restrict__ fp8n,
                                                   f16* __restrict__ Yh,
                                                   float* __restrict__ base) {
    __shared__ f16 wlds[256 * 128];  // Wcat[col][k], chunk-swizzled: chunk ^= (col&15)
    int tid = threadIdx.x;

    // stage W (128x256 f32) -> LDS as f16 concat layout, coalesced 32B reads per thread
    #pragma unroll
    for (int it = 0; it < 8; ++it) {
        int g = tid + it * 512;          // 8-float group, 4096 total
        int i = g * 8;                   // flat index into W
        int c_w = i >> 8;                // W row (0..127)
        int kk = i & 255;                // W col (0..255)
        int destrow = (kk < 128) ? c_w : c_w + 128;
        int k = kk & 127;
        int chunk = (k >> 3) ^ (destrow & 15);
        f32x4 v0 = *(const f32x4*)(W + i);
        f32x4 v1 = *(const f32x4*)(W + i + 4);
        f16x8 h;
        #pragma unroll
        for (int e = 0; e < 4; ++e) { h[e] = (f16)v0[e]; h[4 + e] = (f16)v1[e]; }
        *(f16x8*)(wlds + destrow * 128 + chunk * 8) = h;
    }
    __syncthreads();

    int wid = tid >> 6, lane = tid & 63;
    int row0 = blockIdx.x * 128 + wid * 16;
    if (row0 >= NROWS) return;           // no barriers after this point
    int r = lane & 15, kg = lane >> 4;

    // load row slices f32, compute sum-of-squares
    const float* src = fp + (size_t)(row0 + r) * D + kg * 8;
    f32x4 v[8];
    float ssq = 0.f;
    #pragma unroll
    for (int kc = 0; kc < 4; ++kc) {
        v[2 * kc]     = *(const f32x4*)(src + kc * 32);
        v[2 * kc + 1] = *(const f32x4*)(src + kc * 32 + 4);
        #pragma unroll
        for (int e = 0; e < 4; ++e) {
            ssq = fmaf(v[2 * kc][e], v[2 * kc][e], ssq);
            ssq = fmaf(v[2 * kc + 1][e], v[2 * kc + 1][e], ssq);
        }
    }
    ssq += __shfl_xor(ssq, 16, 64);
    ssq += __shfl_xor(ssq, 32, 64);      // all lanes: full row ssq
    float rn = rsqrtf(ssq);

    // A-frags (f16, unnormalized) for MFMA + fp8 e4m3 normalized row for the cosine table
    f16x8 a[4];
    #pragma unroll
    for (int kc = 0; kc < 4; ++kc) {
        f16x8 h;
        float nx[8];
        #pragma unroll
        for (int e = 0; e < 4; ++e) {
            float x0 = v[2 * kc][e], x1 = v[2 * kc + 1][e];
            h[e] = (f16)x0;        h[4 + e] = (f16)x1;
            nx[e] = x0 * rn;       nx[4 + e] = x1 * rn;
        }
        a[kc] = h;
        u32 lo = __builtin_amdgcn_cvt_pk_fp8_f32(nx[0], nx[1], 0u, false);
        lo     = __builtin_amdgcn_cvt_pk_fp8_f32(nx[2], nx[3], lo, true);
        u32 hi = __builtin_amdgcn_cvt_pk_fp8_f32(nx[4], nx[5], 0u, false);
        hi     = __builtin_amdgcn_cvt_pk_fp8_f32(nx[6], nx[7], hi, true);
        uint2 st; st.x = lo; st.y = hi;
        *(uint2*)(fp8n + (size_t)(row0 + r) * 128 + kc * 32 + kg * 8) = st;
    }

    #pragma unroll 4
    for (int ct = 0; ct < 16; ++ct) {
        int col = ct * 16 + r;
        f32x4 acc = {0.f, 0.f, 0.f, 0.f};
        #pragma unroll
        for (int kc = 0; kc < 4; ++kc) {
            int sc = (kc * 4 + kg) ^ r;  // swizzled chunk (matches staging XOR)
            f16x8 bf = *(const f16x8*)(wlds + col * 128 + sc * 8);
            acc = __builtin_amdgcn_mfma_f32_16x16x32_f16(a[kc], bf, acc, 0, 0, 0);
        }
        // C/D: col = lane&15 -> output channel; rows = row0 + kg*4 + i
        if (col < 128) {
            #pragma unroll
            for (int i = 0; i < 4; ++i)
                Yh[(size_t)(row0 + kg * 4 + i) * D + col] = (f16)acc[i];
        } else {
            float bias = b[col - 128];
            #pragma unroll
            for (int i = 0; i < 4; ++i)
                base[(size_t)(row0 + kg * 4 + i) * D + (col - 128)] = acc[i] + bias;
        }
    }
}

// ---- main: one wave per n; all 16 Y-gathers issued first; fp8 cosine dots ----
__global__ __launch_bounds__(256) void main_kernel(const unsigned char* __restrict__ fp8n,
                                                   const int* __restrict__ idx,
                                                   const f16* __restrict__ Yh,
                                                   float* __restrict__ out) {
    int wid = threadIdx.x >> 6, lane = threadIdx.x & 63;
    int n = blockIdx.x * 4 + wid;
    int s = lane & 3, k = lane >> 2;

    int j = idx[n * KNB + k];

    // issue the full Y gather set up front (memory-level parallelism)
    f16x2 yv[16];
    #pragma unroll
    for (int kk = 0; kk < KNB; ++kk) {
        int jk = __shfl(j, kk * 4, 64);
        yv[kk] = *(const f16x2*)(Yh + (size_t)jk * D + lane * 2);
    }
    float2 bv = *(const float2*)(out + (size_t)n * D + lane * 2);

    // cosine dot on fp8-normalized rows: lane = (k, 32-elem slice s); w = dot directly
    const uint4* pj = (const uint4*)(fp8n + (size_t)j * 128 + s * 32);
    const uint4* pn = (const uint4*)(fp8n + (size_t)n * 128 + s * 32);
    uint4 xa = pj[0], xb = pj[1];
    uint4 ya = pn[0], yb = pn[1];
    float p = 0.f;
    auto dot4 = [&p](u32 xw, u32 yw) {
        f32x2 x0 = __builtin_amdgcn_cvt_pk_f32_fp8(xw, false);
        f32x2 x1 = __builtin_amdgcn_cvt_pk_f32_fp8(xw, true);
        f32x2 y0 = __builtin_amdgcn_cvt_pk_f32_fp8(yw, false);
        f32x2 y1 = __builtin_amdgcn_cvt_pk_f32_fp8(yw, true);
        p = fmaf(x0.x, y0.x, p); p = fmaf(x0.y, y0.y, p);
        p = fmaf(x1.x, y1.x, p); p = fmaf(x1.y, y1.y, p);
    };
    dot4(xa.x, ya.x); dot4(xa.y, ya.y); dot4(xa.z, ya.z); dot4(xa.w, ya.w);
    dot4(xb.x, yb.x); dot4(xb.y, yb.y); dot4(xb.z, yb.z); dot4(xb.w, yb.w);
    p += __shfl_xor(p, 1, 64);
    p += __shfl_xor(p, 2, 64);

    // combine: lane owns cols 2*lane, 2*lane+1
    float a0 = -INFINITY, a1 = -INFINITY;
    #pragma unroll
    for (int kk = 0; kk < KNB; ++kk) {
        float wk = __shfl(p, kk * 4, 64);
        a0 = fmaxf(a0, ((float)yv[kk].x + bv.x) * wk);
        a1 = fmaxf(a1, ((float)yv[kk].y + bv.y) * wk);
    }
    *(float2*)(out + (size_t)n * D + lane * 2) = make_float2(a0, a1);
}

extern "C" void kernel_launch(void* const* d_in, const int* in_sizes, int n_in,
                              void* d_out, int out_size, void* d_ws, size_t ws_size,
                              hipStream_t stream) {
    const float* fp  = (const float*)d_in[0];   // (N,128) f32
    const int*   idx = (const int*)d_in[1];     // (N,16) int32
    const float* W   = (const float*)d_in[2];   // (128,256) f32
    const float* b   = (const float*)d_in[3];   // (128,) f32
    float* out = (float*)d_out;                 // (N,128) f32; holds base between kernels

    char* ws = (char*)d_ws;
    unsigned char* fp8n = (unsigned char*)ws;              // 6.4 MB (fp8 e4m3 normalized rows)
    f16* Yh = (f16*)(ws + (size_t)NROWS * 128);            // 12.8 MB

    gemm_kernel<<<(NROWS + 127) / 128, 512, 0, stream>>>(fp, W, b, fp8n, Yh, out);
    main_kernel<<<NROWS / 4, 256, 0, stream>>>(fp8n, idx, Yh, out);
}